// Round 2
// baseline (397.646 us; speedup 1.0000x reference)
//
#include <hip/hip_runtime.h>
#include <math.h>

#define NB 32
#define C 256
#define H 64
#define W 64
#define HW 4096
#define K4_TILES 50  // 1600 o-rows / 32 per tile

// ---------------------------------------------------------------------------
// K1: per-(n,c) global max of relu(x) -> t3   [+ one extra block computes
//     w2bar[c] = mean_o W2[o,c] ]
// ---------------------------------------------------------------------------
__global__ __launch_bounds__(256) void k1_t3_prep(
    const float* __restrict__ x, const float* __restrict__ W2,
    float* __restrict__ w2bar, float* __restrict__ t3) {
  int b = blockIdx.x;
  int tid = threadIdx.x;
  if (b == NB * C) {
    float s = 0.f;
    for (int o = 0; o < C; ++o) s += W2[o * C + tid];
    w2bar[tid] = s * (1.0f / (float)C);
    return;
  }
  const float4* xv = (const float4*)(x + (size_t)b * HW);
  float m = -3.4e38f;
#pragma unroll
  for (int i = 0; i < 4; ++i) {
    float4 v = xv[i * 256 + tid];
    m = fmaxf(m, fmaxf(fmaxf(v.x, v.y), fmaxf(v.z, v.w)));
  }
  for (int off = 32; off > 0; off >>= 1)
    m = fmaxf(m, __shfl_down(m, off, 64));
  __shared__ float sm[4];
  if ((tid & 63) == 0) sm[tid >> 6] = m;
  __syncthreads();
  if (tid == 0) {
    float mm = fmaxf(fmaxf(sm[0], sm[1]), fmaxf(sm[2], sm[3]));
    t3[b] = fmaxf(mm, 0.0f);
  }
}

// ---------------------------------------------------------------------------
// K2: one streaming pass over x -> t5, t13
// ---------------------------------------------------------------------------
__global__ __launch_bounds__(256) void k2_s_t9(
    const float* __restrict__ x, const float* __restrict__ w2bar,
    const float* __restrict__ t3, const float* __restrict__ p4,
    const float* __restrict__ p13, float* __restrict__ t5,
    float* __restrict__ t13) {
  int n = blockIdx.x >> 4;
  int p = ((blockIdx.x & 15) << 8) | threadIdx.x;
  __shared__ float sw[C];
  __shared__ float st[C];
  sw[threadIdx.x] = w2bar[threadIdx.x];
  st[threadIdx.x] = t3[n * C + threadIdx.x];
  __syncthreads();
  const float* xp = x + (size_t)n * C * HW + p;
  float accs = 0.f, acc9 = 0.f;
#pragma unroll 16
  for (int c = 0; c < C; ++c) {
    float v = xp[(size_t)c * HW];
    accs = fmaf(sw[c], fmaxf(v, 0.f), accs);
    acc9 = fmaf(st[c], v, acc9);
  }
  t5[n * HW + p] = p4[p] * accs;
  t13[n * HW + p] = p13[p] * acc9;
}

// ---------------------------------------------------------------------------
// K3: per n: column maxima of t5, t7, t8 = W8 @ t7
// ---------------------------------------------------------------------------
__global__ __launch_bounds__(256) void k3_t8(
    const float* __restrict__ t5, const float* __restrict__ W8,
    float* __restrict__ t8) {
  int n = blockIdx.x >> 2;
  int og = (blockIdx.x & 3) << 6;
  int tid = threadIdx.x;
  __shared__ float s5[HW];
  __shared__ float cm[5][64];
  __shared__ float t7s[25][64];
  const float4* t5v = (const float4*)(t5 + n * HW);
  float4* s5v = (float4*)s5;
#pragma unroll
  for (int i = 0; i < 4; ++i) s5v[i * 256 + tid] = t5v[i * 256 + tid];
  __syncthreads();
  for (int idx = tid; idx < 5 * 64; idx += 256) {
    int ki = idx >> 6, wp = idx & 63;
    int lo = max(0, 3 * ki - 6), hi = min(63, 3 * ki + 57);
    float m = (ki == 2) ? -3.4e38f : 0.0f;
    for (int hp = lo; hp <= hi; ++hp) m = fmaxf(m, s5[hp * 64 + wp]);
    cm[ki][wp] = m;
  }
  __syncthreads();
  for (int idx = tid; idx < 25 * 64; idx += 256) {
    int k = idx >> 6, w = idx & 63;
    int ki = k / 5, kj = k % 5;
    int wp = w + 3 * kj - 6;
    t7s[k][w] = (wp >= 0 && wp < 64) ? cm[ki][wp] : 0.0f;
  }
  __syncthreads();
  int w = tid & 63, orow = tid >> 6;
  for (int i = 0; i < 16; ++i) {
    int o = og + orow * 16 + i;
    float acc = 0.f;
#pragma unroll
    for (int k = 0; k < 25; ++k) acc = fmaf(W8[o * 25 + k], t7s[k][w], acc);
    t8[(n * C + o) * 64 + w] = acc;
  }
}

// ---------------------------------------------------------------------------
// K4 v2: t10 = W10 @ t8 (per n), fused gelu + t6-add + column max.
//   50 tiles of 32 o-rows (acc[8]/thread); t8 staged in 4x 16KB chunks so
//   LDS no longer caps occupancy (was 64KB -> 2 blocks/CU -> latency-bound).
// ---------------------------------------------------------------------------
__global__ __launch_bounds__(256) void k4_t10max(
    const float* __restrict__ t8, const float* __restrict__ W10,
    const float* __restrict__ t5, float* __restrict__ part) {
  int n = blockIdx.x / K4_TILES;
  int tile = blockIdx.x - n * K4_TILES;
  int tid = threadIdx.x;
  int w = tid & 63, r = tid >> 6;
  __shared__ float t8s[64 * 64];  // 16KB chunk: 64 channels x 64 w
  __shared__ float red[256];
  float acc[8];
#pragma unroll
  for (int j = 0; j < 8; ++j) acc[j] = 0.f;
  int o0 = tile * 32 + r * 8;
  const float4* w10v = (const float4*)W10;  // rows of 64 float4
  for (int ch = 0; ch < 4; ++ch) {
    const float4* src = (const float4*)(t8 + ((size_t)n * C + ch * 64) * 64);
    float4* dst = (float4*)t8s;
#pragma unroll
    for (int i = 0; i < 4; ++i) dst[i * 256 + tid] = src[i * 256 + tid];
    __syncthreads();
#pragma unroll 4
    for (int c4 = 0; c4 < 16; ++c4) {
      float v0 = t8s[(c4 * 4 + 0) * 64 + w];
      float v1 = t8s[(c4 * 4 + 1) * 64 + w];
      float v2 = t8s[(c4 * 4 + 2) * 64 + w];
      float v3 = t8s[(c4 * 4 + 3) * 64 + w];
#pragma unroll
      for (int j = 0; j < 8; ++j) {
        float4 a = w10v[(size_t)(o0 + j) * 64 + ch * 16 + c4];
        acc[j] = fmaf(a.x, v0, fmaf(a.y, v1, fmaf(a.z, v2, fmaf(a.w, v3, acc[j]))));
      }
    }
    __syncthreads();
  }
  const float* t5n = t5 + n * HW;
  float pmax = -3.4e38f;
#pragma unroll
  for (int j = 0; j < 8; ++j) {
    int o = o0 + j;
    int k = o >> 6, h = o & 63;
    int ki = k / 5, kj = k - ki * 5;
    int hp = h + 3 * ki - 6, wp = w + 3 * kj - 6;
    float t6v = (hp >= 0 && hp < 64 && wp >= 0 && wp < 64)
                    ? t5n[hp * 64 + wp] : 0.0f;
    float xg = acc[j];
    float gl = 0.5f * xg * (1.0f + erff(xg * 0.70710678118654752f));
    pmax = fmaxf(pmax, t6v + gl);
  }
  red[r * 64 + w] = pmax;
  __syncthreads();
  if (r == 0) {
    float m = fmaxf(fmaxf(red[w], red[64 + w]), fmaxf(red[128 + w], red[192 + w]));
    part[(n * K4_TILES + tile) * 64 + w] = m;
  }
}

// ---------------------------------------------------------------------------
// K5: M[n,w'] = exp(max over tile partials); t17[n,w] = mean_j of valid M
// ---------------------------------------------------------------------------
__global__ __launch_bounds__(64) void k5_t17(
    const float* __restrict__ part, float* __restrict__ t17) {
  int n = blockIdx.x;
  int w = threadIdx.x;
  float m = -3.4e38f;
#pragma unroll
  for (int t = 0; t < K4_TILES; ++t)
    m = fmaxf(m, part[(n * K4_TILES + t) * 64 + w]);
  __shared__ float M[64];
  M[w] = expf(m);
  __syncthreads();
  float s = 0.f;
#pragma unroll
  for (int j = 0; j < 7; ++j) {
    int wp = w + 3 * j - 9;
    if (wp >= 0 && wp < 64) s += M[wp];
  }
  t17[n * 64 + w] = s * (1.0f / 7.0f);
}

// ---------------------------------------------------------------------------
// K6: out[n,c,h,w] = t13[n,h,w] - W18[c*64+h] * t17[n,w]
// ---------------------------------------------------------------------------
__global__ __launch_bounds__(256) void k6_out(
    const float* __restrict__ t13, const float* __restrict__ t17,
    const float* __restrict__ W18, float* __restrict__ out) {
  int b = blockIdx.x;  // n*C + c
  int n = b >> 8, c = b & 255;
  int tid = threadIdx.x;
  const float4* t13v = (const float4*)(t13 + n * HW);
  const float4* t17v = (const float4*)(t17 + n * 64);
  float4* outv = (float4*)(out + (size_t)b * HW);
#pragma unroll
  for (int i = 0; i < 4; ++i) {
    int idx = i * 256 + tid;
    int h = idx >> 4;
    int w4 = idx & 15;
    float w18 = W18[c * 64 + h];
    float4 a = t13v[idx];
    float4 tt = t17v[w4];
    float4 o;
    o.x = a.x - w18 * tt.x;
    o.y = a.y - w18 * tt.y;
    o.z = a.z - w18 * tt.z;
    o.w = a.w - w18 * tt.w;
    outv[idx] = o;
  }
}

// ---------------------------------------------------------------------------
extern "C" void kernel_launch(void* const* d_in, const int* in_sizes, int n_in,
                              void* d_out, int out_size, void* d_ws,
                              size_t ws_size, hipStream_t stream) {
  const float* x   = (const float*)d_in[0];
  const float* W2  = (const float*)d_in[1];
  const float* W8  = (const float*)d_in[2];
  const float* W10 = (const float*)d_in[3];
  const float* W18 = (const float*)d_in[4];
  const float* p4  = (const float*)d_in[5];
  const float* p13 = (const float*)d_in[6];
  float* out = (float*)d_out;

  float* ws    = (float*)d_ws;
  float* w2bar = ws;                        // 256
  float* t3    = w2bar + 256;               // 32*256
  float* t5    = t3 + NB * C;               // 32*4096
  float* t13   = t5 + NB * HW;              // 32*4096
  float* t8    = t13 + NB * HW;             // 32*256*64
  float* part  = t8 + NB * C * 64;          // 32*K4_TILES*64
  float* t17   = part + NB * K4_TILES * 64; // 32*64

  k1_t3_prep<<<dim3(NB * C + 1), dim3(256), 0, stream>>>(x, W2, w2bar, t3);
  k2_s_t9<<<dim3(NB * 16), dim3(256), 0, stream>>>(x, w2bar, t3, p4, p13, t5, t13);
  k3_t8<<<dim3(NB * 4), dim3(256), 0, stream>>>(t5, W8, t8);
  k4_t10max<<<dim3(NB * K4_TILES), dim3(256), 0, stream>>>(t8, W10, t5, part);
  k5_t17<<<dim3(NB), dim3(64), 0, stream>>>(part, t17);
  k6_out<<<dim3(NB * C), dim3(256), 0, stream>>>(t13, t17, W18, out);
}

// Round 3
// 331.284 us; speedup vs baseline: 1.2003x; 1.2003x over previous
//
#include <hip/hip_runtime.h>
#include <math.h>

#define NB 32
#define C 256
#define H 64
#define W 64
#define HW 4096
#define K4_TILES 25  // 1600 o-rows / 64 per tile

// ---------------------------------------------------------------------------
// K1: per-(n,c) global max of relu(x) -> t3   [+ one extra block computes
//     w2bar[c] = mean_o W2[o,c] ]
// ---------------------------------------------------------------------------
__global__ __launch_bounds__(256) void k1_t3_prep(
    const float* __restrict__ x, const float* __restrict__ W2,
    float* __restrict__ w2bar, float* __restrict__ t3) {
  int b = blockIdx.x;
  int tid = threadIdx.x;
  if (b == NB * C) {
    float s = 0.f;
    for (int o = 0; o < C; ++o) s += W2[o * C + tid];
    w2bar[tid] = s * (1.0f / (float)C);
    return;
  }
  const float4* xv = (const float4*)(x + (size_t)b * HW);
  float m = -3.4e38f;
#pragma unroll
  for (int i = 0; i < 4; ++i) {
    float4 v = xv[i * 256 + tid];
    m = fmaxf(m, fmaxf(fmaxf(v.x, v.y), fmaxf(v.z, v.w)));
  }
  for (int off = 32; off > 0; off >>= 1)
    m = fmaxf(m, __shfl_down(m, off, 64));
  __shared__ float sm[4];
  if ((tid & 63) == 0) sm[tid >> 6] = m;
  __syncthreads();
  if (tid == 0) {
    float mm = fmaxf(fmaxf(sm[0], sm[1]), fmaxf(sm[2], sm[3]));
    t3[b] = fmaxf(mm, 0.0f);
  }
}

// ---------------------------------------------------------------------------
// K2: one streaming pass over x -> t5, t13
// ---------------------------------------------------------------------------
__global__ __launch_bounds__(256) void k2_s_t9(
    const float* __restrict__ x, const float* __restrict__ w2bar,
    const float* __restrict__ t3, const float* __restrict__ p4,
    const float* __restrict__ p13, float* __restrict__ t5,
    float* __restrict__ t13) {
  int n = blockIdx.x >> 4;
  int p = ((blockIdx.x & 15) << 8) | threadIdx.x;
  __shared__ float sw[C];
  __shared__ float st[C];
  sw[threadIdx.x] = w2bar[threadIdx.x];
  st[threadIdx.x] = t3[n * C + threadIdx.x];
  __syncthreads();
  const float* xp = x + (size_t)n * C * HW + p;
  float accs = 0.f, acc9 = 0.f;
#pragma unroll 16
  for (int c = 0; c < C; ++c) {
    float v = xp[(size_t)c * HW];
    accs = fmaf(sw[c], fmaxf(v, 0.f), accs);
    acc9 = fmaf(st[c], v, acc9);
  }
  t5[n * HW + p] = p4[p] * accs;
  t13[n * HW + p] = p13[p] * acc9;
}

// ---------------------------------------------------------------------------
// K3: per n: column maxima of t5, t7, t8 = W8 @ t7
// ---------------------------------------------------------------------------
__global__ __launch_bounds__(256) void k3_t8(
    const float* __restrict__ t5, const float* __restrict__ W8,
    float* __restrict__ t8) {
  int n = blockIdx.x >> 2;
  int og = (blockIdx.x & 3) << 6;
  int tid = threadIdx.x;
  __shared__ float s5[HW];
  __shared__ float cm[5][64];
  __shared__ float t7s[25][64];
  const float4* t5v = (const float4*)(t5 + n * HW);
  float4* s5v = (float4*)s5;
#pragma unroll
  for (int i = 0; i < 4; ++i) s5v[i * 256 + tid] = t5v[i * 256 + tid];
  __syncthreads();
  for (int idx = tid; idx < 5 * 64; idx += 256) {
    int ki = idx >> 6, wp = idx & 63;
    int lo = max(0, 3 * ki - 6), hi = min(63, 3 * ki + 57);
    float m = (ki == 2) ? -3.4e38f : 0.0f;
    for (int hp = lo; hp <= hi; ++hp) m = fmaxf(m, s5[hp * 64 + wp]);
    cm[ki][wp] = m;
  }
  __syncthreads();
  for (int idx = tid; idx < 25 * 64; idx += 256) {
    int k = idx >> 6, w = idx & 63;
    int ki = k / 5, kj = k % 5;
    int wp = w + 3 * kj - 6;
    t7s[k][w] = (wp >= 0 && wp < 64) ? cm[ki][wp] : 0.0f;
  }
  __syncthreads();
  int w = tid & 63, orow = tid >> 6;
  for (int i = 0; i < 16; ++i) {
    int o = og + orow * 16 + i;
    float acc = 0.f;
#pragma unroll
    for (int k = 0; k < 25; ++k) acc = fmaf(W8[o * 25 + k], t7s[k][w], acc);
    t8[(n * C + o) * 64 + w] = acc;
  }
}

// ---------------------------------------------------------------------------
// K4 v3: t10 = W10 @ t8 (per n), fused gelu + t6-add + column max.
//   Block = 64 o-rows x 64 w; thread = 4 rows x 4 w (float4 regs).
//   Per c4-iter: 4 global b128 (W10) + 4 LDS b128 (t8) + 64 FMA -> 16:1.
// ---------------------------------------------------------------------------
__global__ __launch_bounds__(256) void k4_t10max(
    const float* __restrict__ t8, const float* __restrict__ W10,
    const float* __restrict__ t5, float* __restrict__ part) {
  int n = blockIdx.x / K4_TILES;
  int tile = blockIdx.x - n * K4_TILES;
  int tid = threadIdx.x;
  int wg = tid & 15, w0 = wg * 4;
  int rg = tid >> 4;                 // 16 row-groups of 4 rows
  int o0 = tile * 64 + rg * 4;
  __shared__ float t8s[64 * 64];     // 16 KB chunk [c_local][w]
  float4 acc[4];
#pragma unroll
  for (int j = 0; j < 4; ++j) acc[j] = make_float4(0.f, 0.f, 0.f, 0.f);
  const float4* w10v = (const float4*)W10;  // row stride 64 float4

  for (int ch = 0; ch < 4; ++ch) {
    const float4* src = (const float4*)(t8 + ((size_t)n * C + ch * 64) * 64);
    float4* dst = (float4*)t8s;
#pragma unroll
    for (int i = 0; i < 4; ++i) dst[i * 256 + tid] = src[i * 256 + tid];
    __syncthreads();
#pragma unroll 4
    for (int c4 = 0; c4 < 16; ++c4) {
      float4 tv0 = *(const float4*)&t8s[(c4 * 4 + 0) * 64 + w0];
      float4 tv1 = *(const float4*)&t8s[(c4 * 4 + 1) * 64 + w0];
      float4 tv2 = *(const float4*)&t8s[(c4 * 4 + 2) * 64 + w0];
      float4 tv3 = *(const float4*)&t8s[(c4 * 4 + 3) * 64 + w0];
#pragma unroll
      for (int j = 0; j < 4; ++j) {
        float4 a = w10v[(size_t)(o0 + j) * 64 + ch * 16 + c4];
        acc[j].x = fmaf(a.x, tv0.x, fmaf(a.y, tv1.x, fmaf(a.z, tv2.x, fmaf(a.w, tv3.x, acc[j].x))));
        acc[j].y = fmaf(a.x, tv0.y, fmaf(a.y, tv1.y, fmaf(a.z, tv2.y, fmaf(a.w, tv3.y, acc[j].y))));
        acc[j].z = fmaf(a.x, tv0.z, fmaf(a.y, tv1.z, fmaf(a.z, tv2.z, fmaf(a.w, tv3.z, acc[j].z))));
        acc[j].w = fmaf(a.x, tv0.w, fmaf(a.y, tv1.w, fmaf(a.z, tv2.w, fmaf(a.w, tv3.w, acc[j].w))));
      }
    }
    __syncthreads();
  }

  // epilogue: t6 + gelu, max over the 4 rows this thread owns, per w
  const float* t5n = t5 + n * HW;
  float pm[4] = {-3.4e38f, -3.4e38f, -3.4e38f, -3.4e38f};
#pragma unroll
  for (int j = 0; j < 4; ++j) {
    int o = o0 + j;
    int k = o >> 6, h = o & 63;
    int ki = k / 5, kj = k - ki * 5;
    int hp = h + 3 * ki - 6;
    float av[4] = {acc[j].x, acc[j].y, acc[j].z, acc[j].w};
#pragma unroll
    for (int e = 0; e < 4; ++e) {
      int wp = w0 + e + 3 * kj - 6;
      float t6v = (hp >= 0 && hp < 64 && wp >= 0 && wp < 64)
                      ? t5n[hp * 64 + wp] : 0.0f;
      float xg = av[e];
      float gl = 0.5f * xg * (1.0f + erff(xg * 0.70710678118654752f));
      pm[e] = fmaxf(pm[e], t6v + gl);
    }
  }
  // reduce over 16 row-groups via LDS (reuse t8s)
  float* red = t8s;  // 16 x 64
#pragma unroll
  for (int e = 0; e < 4; ++e) red[rg * 64 + w0 + e] = pm[e];
  __syncthreads();
  if (tid < 64) {
    float m = -3.4e38f;
#pragma unroll
    for (int g = 0; g < 16; ++g) m = fmaxf(m, red[g * 64 + tid]);
    part[(n * K4_TILES + tile) * 64 + tid] = m;
  }
}

// ---------------------------------------------------------------------------
// K5: M[n,w'] = exp(max over tile partials); t17[n,w] = mean_j of valid M
// ---------------------------------------------------------------------------
__global__ __launch_bounds__(64) void k5_t17(
    const float* __restrict__ part, float* __restrict__ t17) {
  int n = blockIdx.x;
  int w = threadIdx.x;
  float m = -3.4e38f;
#pragma unroll
  for (int t = 0; t < K4_TILES; ++t)
    m = fmaxf(m, part[(n * K4_TILES + t) * 64 + w]);
  __shared__ float M[64];
  M[w] = expf(m);
  __syncthreads();
  float s = 0.f;
#pragma unroll
  for (int j = 0; j < 7; ++j) {
    int wp = w + 3 * j - 9;
    if (wp >= 0 && wp < 64) s += M[wp];
  }
  t17[n * 64 + w] = s * (1.0f / 7.0f);
}

// ---------------------------------------------------------------------------
// K6: out[n,c,h,w] = t13[n,h,w] - W18[c*64+h] * t17[n,w]
// ---------------------------------------------------------------------------
__global__ __launch_bounds__(256) void k6_out(
    const float* __restrict__ t13, const float* __restrict__ t17,
    const float* __restrict__ W18, float* __restrict__ out) {
  int b = blockIdx.x;  // n*C + c
  int n = b >> 8, c = b & 255;
  int tid = threadIdx.x;
  const float4* t13v = (const float4*)(t13 + n * HW);
  const float4* t17v = (const float4*)(t17 + n * 64);
  float4* outv = (float4*)(out + (size_t)b * HW);
#pragma unroll
  for (int i = 0; i < 4; ++i) {
    int idx = i * 256 + tid;
    int h = idx >> 4;
    int w4 = idx & 15;
    float w18 = W18[c * 64 + h];
    float4 a = t13v[idx];
    float4 tt = t17v[w4];
    float4 o;
    o.x = a.x - w18 * tt.x;
    o.y = a.y - w18 * tt.y;
    o.z = a.z - w18 * tt.z;
    o.w = a.w - w18 * tt.w;
    outv[idx] = o;
  }
}

// ---------------------------------------------------------------------------
extern "C" void kernel_launch(void* const* d_in, const int* in_sizes, int n_in,
                              void* d_out, int out_size, void* d_ws,
                              size_t ws_size, hipStream_t stream) {
  const float* x   = (const float*)d_in[0];
  const float* W2  = (const float*)d_in[1];
  const float* W8  = (const float*)d_in[2];
  const float* W10 = (const float*)d_in[3];
  const float* W18 = (const float*)d_in[4];
  const float* p4  = (const float*)d_in[5];
  const float* p13 = (const float*)d_in[6];
  float* out = (float*)d_out;

  float* ws    = (float*)d_ws;
  float* w2bar = ws;                        // 256
  float* t3    = w2bar + 256;               // 32*256
  float* t5    = t3 + NB * C;               // 32*4096
  float* t13   = t5 + NB * HW;              // 32*4096
  float* t8    = t13 + NB * HW;             // 32*256*64
  float* part  = t8 + NB * C * 64;          // 32*K4_TILES*64
  float* t17   = part + NB * K4_TILES * 64; // 32*64

  k1_t3_prep<<<dim3(NB * C + 1), dim3(256), 0, stream>>>(x, W2, w2bar, t3);
  k2_s_t9<<<dim3(NB * 16), dim3(256), 0, stream>>>(x, w2bar, t3, p4, p13, t5, t13);
  k3_t8<<<dim3(NB * 4), dim3(256), 0, stream>>>(t5, W8, t8);
  k4_t10max<<<dim3(NB * K4_TILES), dim3(256), 0, stream>>>(t8, W10, t5, part);
  k5_t17<<<dim3(NB), dim3(64), 0, stream>>>(part, t17);
  k6_out<<<dim3(NB * C), dim3(256), 0, stream>>>(t13, t17, W18, out);
}

// Round 4
// 311.531 us; speedup vs baseline: 1.2764x; 1.0634x over previous
//
#include <hip/hip_runtime.h>
#include <math.h>

#define NB 32
#define C 256
#define H 64
#define W 64
#define HW 4096
#define KT 25  // 25 unfold tiles of 64 o-rows

// ---------------------------------------------------------------------------
// K0: WW[o][kk] = sum_c W10[o][c] * W8[c][kk]   (1600 x 25, K=256)
// ---------------------------------------------------------------------------
__global__ __launch_bounds__(256) void k0_ww(
    const float* __restrict__ W10, const float* __restrict__ W8,
    float* __restrict__ WW) {
  __shared__ float s8[256 * 25];  // 25.6 KB
  int tid = threadIdx.x;
  for (int i = tid; i < 6400; i += 256) s8[i] = W8[i];
  __syncthreads();
  int idx = blockIdx.x * 256 + tid;
  if (idx >= 1600 * 25) return;
  int o = idx / 25, kk = idx - o * 25;
  const float* wrow = W10 + (size_t)o * 256;
  float acc = 0.f;
#pragma unroll 8
  for (int c = 0; c < 256; ++c) acc = fmaf(wrow[c], s8[c * 25 + kk], acc);
  WW[idx] = acc;
}

// ---------------------------------------------------------------------------
// K1: per-(n,c) global max of relu(x) -> t3   [+ one extra block computes
//     w2bar[c] = mean_o W2[o,c] ]
// ---------------------------------------------------------------------------
__global__ __launch_bounds__(256) void k1_t3_prep(
    const float* __restrict__ x, const float* __restrict__ W2,
    float* __restrict__ w2bar, float* __restrict__ t3) {
  int b = blockIdx.x;
  int tid = threadIdx.x;
  if (b == NB * C) {
    float s = 0.f;
    for (int o = 0; o < C; ++o) s += W2[o * C + tid];
    w2bar[tid] = s * (1.0f / (float)C);
    return;
  }
  const float4* xv = (const float4*)(x + (size_t)b * HW);
  float m = -3.4e38f;
#pragma unroll
  for (int i = 0; i < 4; ++i) {
    float4 v = xv[i * 256 + tid];
    m = fmaxf(m, fmaxf(fmaxf(v.x, v.y), fmaxf(v.z, v.w)));
  }
  for (int off = 32; off > 0; off >>= 1)
    m = fmaxf(m, __shfl_down(m, off, 64));
  __shared__ float sm[4];
  if ((tid & 63) == 0) sm[tid >> 6] = m;
  __syncthreads();
  if (tid == 0) {
    float mm = fmaxf(fmaxf(sm[0], sm[1]), fmaxf(sm[2], sm[3]));
    t3[b] = fmaxf(mm, 0.0f);
  }
}

// ---------------------------------------------------------------------------
// K2: one streaming pass over x -> t5, t13
// ---------------------------------------------------------------------------
__global__ __launch_bounds__(256) void k2_s_t9(
    const float* __restrict__ x, const float* __restrict__ w2bar,
    const float* __restrict__ t3, const float* __restrict__ p4,
    const float* __restrict__ p13, float* __restrict__ t5,
    float* __restrict__ t13) {
  int n = blockIdx.x >> 4;
  int p = ((blockIdx.x & 15) << 8) | threadIdx.x;
  __shared__ float sw[C];
  __shared__ float st[C];
  sw[threadIdx.x] = w2bar[threadIdx.x];
  st[threadIdx.x] = t3[n * C + threadIdx.x];
  __syncthreads();
  const float* xp = x + (size_t)n * C * HW + p;
  float accs = 0.f, acc9 = 0.f;
#pragma unroll 16
  for (int c = 0; c < C; ++c) {
    float v = xp[(size_t)c * HW];
    accs = fmaf(sw[c], fmaxf(v, 0.f), accs);
    acc9 = fmaf(st[c], v, acc9);
  }
  t5[n * HW + p] = p4[p] * accs;
  t13[n * HW + p] = p13[p] * acc9;
}

// ---------------------------------------------------------------------------
// K4 v4 (fused, WW-collapsed): per block (n, k):
//   stage t5[n] (16KB) + WW rows k*64..k*64+63 (6.4KB);
//   cm (5x64 col maxima of t5 with zero-pad) -> t7 (25x64);
//   t10[h][w] = sum_kk WW[k*64+h][kk] * t7[kk][w]   (K=25);
//   out-tile max over h of (t6 + gelu(t10)) -> part[n][k][w].
// ---------------------------------------------------------------------------
__global__ __launch_bounds__(256) void k4_fused(
    const float* __restrict__ t5g, const float* __restrict__ WW,
    float* __restrict__ part) {
  int n = blockIdx.x / KT;
  int k = blockIdx.x - n * KT;
  int ki = k / 5, kj = k - ki * 5;
  int tid = threadIdx.x;
  int wg = tid & 15, w0 = wg * 4;
  int rg = tid >> 4, h0 = rg * 4;
  __shared__ float s5[HW];         // 16 KB
  __shared__ float ww[64 * 25];    // 6.4 KB  [h][kk]
  __shared__ float t7s[25 * 64];   // 6.4 KB  [kk][w]
  __shared__ float cm[5 * 64];

  const float4* t5v = (const float4*)(t5g + n * HW);
  float4* s5v = (float4*)s5;
#pragma unroll
  for (int i = 0; i < 4; ++i) s5v[i * 256 + tid] = t5v[i * 256 + tid];
  const float* wwsrc = WW + (size_t)k * 64 * 25;
  for (int i = tid; i < 1600; i += 256) ww[i] = wwsrc[i];
  __syncthreads();

  // cm[kii][wp]: max over valid h-window; zero participates when padded
  for (int idx = tid; idx < 5 * 64; idx += 256) {
    int kii = idx >> 6, wp = idx & 63;
    int lo = max(0, 3 * kii - 6), hi = min(63, 3 * kii + 57);
    float m = (kii == 2) ? -3.4e38f : 0.0f;
    for (int hp = lo; hp <= hi; ++hp) m = fmaxf(m, s5[hp * 64 + wp]);
    cm[kii * 64 + wp] = m;
  }
  __syncthreads();
  for (int idx = tid; idx < 25 * 64; idx += 256) {
    int kk = idx >> 6, w = idx & 63;
    int kki = kk / 5, kkj = kk - kki * 5;
    int wp = w + 3 * kkj - 6;
    t7s[kk * 64 + w] = (wp >= 0 && wp < 64) ? cm[kki * 64 + wp] : 0.0f;
  }
  __syncthreads();

  // 4x4 register-tile GEMM, K=25
  float4 acc[4];
#pragma unroll
  for (int j = 0; j < 4; ++j) acc[j] = make_float4(0.f, 0.f, 0.f, 0.f);
#pragma unroll
  for (int kk = 0; kk < 25; ++kk) {
    float4 tv = *(const float4*)&t7s[kk * 64 + w0];
#pragma unroll
    for (int j = 0; j < 4; ++j) {
      float a = ww[(h0 + j) * 25 + kk];
      acc[j].x = fmaf(a, tv.x, acc[j].x);
      acc[j].y = fmaf(a, tv.y, acc[j].y);
      acc[j].z = fmaf(a, tv.z, acc[j].z);
      acc[j].w = fmaf(a, tv.w, acc[j].w);
    }
  }

  // epilogue: t6 + gelu, max over this thread's 4 h-rows
  int hpb = 3 * ki - 6, wpb = 3 * kj - 6;
  float pm[4] = {-3.4e38f, -3.4e38f, -3.4e38f, -3.4e38f};
#pragma unroll
  for (int j = 0; j < 4; ++j) {
    int hp = h0 + j + hpb;
    float av[4] = {acc[j].x, acc[j].y, acc[j].z, acc[j].w};
#pragma unroll
    for (int e = 0; e < 4; ++e) {
      int wp = w0 + e + wpb;
      float t6v = (hp >= 0 && hp < 64 && wp >= 0 && wp < 64)
                      ? s5[hp * 64 + wp] : 0.0f;
      float xg = av[e];
      float gl = 0.5f * xg * (1.0f + erff(xg * 0.70710678118654752f));
      pm[e] = fmaxf(pm[e], t6v + gl);
    }
  }
  __syncthreads();  // done with t7s -> reuse as reduction scratch
  float* red = t7s;  // 16 x 64
#pragma unroll
  for (int e = 0; e < 4; ++e) red[rg * 64 + w0 + e] = pm[e];
  __syncthreads();
  if (tid < 64) {
    float m = -3.4e38f;
#pragma unroll
    for (int g = 0; g < 16; ++g) m = fmaxf(m, red[g * 64 + tid]);
    part[(n * KT + k) * 64 + tid] = m;
  }
}

// ---------------------------------------------------------------------------
// K5: M[n,w'] = exp(max over 25 tile partials); t17[n,w] = mean_j of valid M
// ---------------------------------------------------------------------------
__global__ __launch_bounds__(64) void k5_t17(
    const float* __restrict__ part, float* __restrict__ t17) {
  int n = blockIdx.x;
  int w = threadIdx.x;
  float m = -3.4e38f;
#pragma unroll
  for (int t = 0; t < KT; ++t)
    m = fmaxf(m, part[(n * KT + t) * 64 + w]);
  __shared__ float M[64];
  M[w] = expf(m);
  __syncthreads();
  float s = 0.f;
#pragma unroll
  for (int j = 0; j < 7; ++j) {
    int wp = w + 3 * j - 9;
    if (wp >= 0 && wp < 64) s += M[wp];
  }
  t17[n * 64 + w] = s * (1.0f / 7.0f);
}

// ---------------------------------------------------------------------------
// K6: out[n,c,h,w] = t13[n,h,w] - W18[c*64+h] * t17[n,w]
// ---------------------------------------------------------------------------
__global__ __launch_bounds__(256) void k6_out(
    const float* __restrict__ t13, const float* __restrict__ t17,
    const float* __restrict__ W18, float* __restrict__ out) {
  int b = blockIdx.x;  // n*C + c
  int n = b >> 8, c = b & 255;
  int tid = threadIdx.x;
  const float4* t13v = (const float4*)(t13 + n * HW);
  const float4* t17v = (const float4*)(t17 + n * 64);
  float4* outv = (float4*)(out + (size_t)b * HW);
#pragma unroll
  for (int i = 0; i < 4; ++i) {
    int idx = i * 256 + tid;
    int h = idx >> 4;
    int w4 = idx & 15;
    float w18 = W18[c * 64 + h];
    float4 a = t13v[idx];
    float4 tt = t17v[w4];
    float4 o;
    o.x = a.x - w18 * tt.x;
    o.y = a.y - w18 * tt.y;
    o.z = a.z - w18 * tt.z;
    o.w = a.w - w18 * tt.w;
    outv[idx] = o;
  }
}

// ---------------------------------------------------------------------------
extern "C" void kernel_launch(void* const* d_in, const int* in_sizes, int n_in,
                              void* d_out, int out_size, void* d_ws,
                              size_t ws_size, hipStream_t stream) {
  const float* x   = (const float*)d_in[0];
  const float* W2  = (const float*)d_in[1];
  const float* W8  = (const float*)d_in[2];
  const float* W10 = (const float*)d_in[3];
  const float* W18 = (const float*)d_in[4];
  const float* p4  = (const float*)d_in[5];
  const float* p13 = (const float*)d_in[6];
  float* out = (float*)d_out;

  float* ws    = (float*)d_ws;
  float* w2bar = ws;                   // 256
  float* t3    = w2bar + 256;          // 32*256
  float* t5    = t3 + NB * C;          // 32*4096
  float* t13   = t5 + NB * HW;         // 32*4096
  float* WW    = t13 + NB * HW;        // 1600*25
  float* part  = WW + 1600 * 25;       // 32*25*64
  float* t17   = part + NB * KT * 64;  // 32*64

  k0_ww<<<dim3(157), dim3(256), 0, stream>>>(W10, W8, WW);
  k1_t3_prep<<<dim3(NB * C + 1), dim3(256), 0, stream>>>(x, W2, w2bar, t3);
  k2_s_t9<<<dim3(NB * 16), dim3(256), 0, stream>>>(x, w2bar, t3, p4, p13, t5, t13);
  k4_fused<<<dim3(NB * KT), dim3(256), 0, stream>>>(t5, WW, part);
  k5_t17<<<dim3(NB), dim3(64), 0, stream>>>(part, t17);
  k6_out<<<dim3(NB * C), dim3(256), 0, stream>>>(t13, t17, W18, out);
}